// Round 1
// baseline (503.909 us; speedup 1.0000x reference)
//
#include <hip/hip_runtime.h>
#include <hip/hip_bf16.h>

#define NCLS 100
#define DIM  512
#define EPSV 1e-8f

// ---------------- histogram of labels ----------------
__global__ __launch_bounds__(256) void hist_kernel(const int* __restrict__ label,
                                                   int* __restrict__ cnt, int n) {
    __shared__ int h[NCLS];
    for (int i = threadIdx.x; i < NCLS; i += 256) h[i] = 0;
    __syncthreads();
    for (int i = blockIdx.x * 256 + threadIdx.x; i < n; i += gridDim.x * 256)
        atomicAdd(&h[label[i]], 1);
    __syncthreads();
    for (int i = threadIdx.x; i < NCLS; i += 256) {
        int v = h[i];
        if (v) atomicAdd(&cnt[i], v);
    }
}

// ---------------- segment sum ----------------
// grid.x = 8 d-chunks of 64 dims, grid.y = row chunks. Block = 256 thr = 4 waves,
// each wave handles one row at a time (lane = dim within chunk, label is wave-uniform).
__global__ __launch_bounds__(256) void segsum_kernel(const float* __restrict__ feat,
                                                     const int* __restrict__ label,
                                                     float* __restrict__ sums, int n) {
    __shared__ float acc[NCLS * 64];   // 25.6 KB
    for (int i = threadIdx.x; i < NCLS * 64; i += 256) acc[i] = 0.0f;
    __syncthreads();

    const int lane  = threadIdx.x & 63;
    const int wv    = threadIdx.x >> 6;           // 0..3
    const int dbase = blockIdx.x * 64;

    const int rows_per = (n + gridDim.y - 1) / gridDim.y;
    const int r0 = blockIdx.y * rows_per;
    const int r1 = min(n, r0 + rows_per);

    int r = r0 + wv;
    // 4x unrolled main loop to keep multiple feat loads in flight
    for (; r + 12 < r1; r += 16) {
        int c0 = label[r];
        int c1 = label[r + 4];
        int c2 = label[r + 8];
        int c3 = label[r + 12];
        float v0 = feat[(size_t)(r     ) * DIM + dbase + lane];
        float v1 = feat[(size_t)(r +  4) * DIM + dbase + lane];
        float v2 = feat[(size_t)(r +  8) * DIM + dbase + lane];
        float v3 = feat[(size_t)(r + 12) * DIM + dbase + lane];
        atomicAdd(&acc[c0 * 64 + lane], v0);
        atomicAdd(&acc[c1 * 64 + lane], v1);
        atomicAdd(&acc[c2 * 64 + lane], v2);
        atomicAdd(&acc[c3 * 64 + lane], v3);
    }
    for (; r < r1; r += 4) {
        int c = label[r];
        float v = feat[(size_t)r * DIM + dbase + lane];
        atomicAdd(&acc[c * 64 + lane], v);
    }
    __syncthreads();

    // flush LDS partials to global sums
    for (int i = threadIdx.x; i < NCLS * 64; i += 256) {
        float v = acc[i];
        if (v != 0.0f)
            atomicAdd(&sums[(size_t)(i >> 6) * DIM + dbase + (i & 63)], v);
    }
}

// ---------------- means + per-class inverse norm ----------------
__global__ __launch_bounds__(256) void finalize_kernel(const float* __restrict__ sums,
                                                       const int* __restrict__ cnt,
                                                       float* __restrict__ means,
                                                       float* __restrict__ qinv) {
    const int c = blockIdx.x;
    const float inv = 1.0f / fmaxf((float)cnt[c], 1.0f);
    __shared__ float red[4];
    float ss = 0.0f;
    for (int d = threadIdx.x; d < DIM; d += 256) {
        float m = sums[(size_t)c * DIM + d] * inv;
        means[(size_t)c * DIM + d] = m;
        ss += m * m;
    }
    #pragma unroll
    for (int off = 32; off; off >>= 1) ss += __shfl_down(ss, off, 64);
    const int wv = threadIdx.x >> 6, ln = threadIdx.x & 63;
    if (ln == 0) red[wv] = ss;
    __syncthreads();
    if (threadIdx.x == 0) {
        float t = red[0] + red[1] + red[2] + red[3];
        qinv[c] = 1.0f / fmaxf(sqrtf(t), EPSV);
    }
}

// ---------------- cosine: one wave per row ----------------
__global__ __launch_bounds__(256) void cos_kernel(const float* __restrict__ feat,
                                                  const int* __restrict__ label,
                                                  const float* __restrict__ means,
                                                  const float* __restrict__ qinv,
                                                  float* __restrict__ out, int n) {
    const int wv   = threadIdx.x >> 6;
    const int lane = threadIdx.x & 63;
    const int row  = blockIdx.x * 4 + wv;
    if (row >= n) return;
    const int c = label[row];

    const float4* f4 = (const float4*)(feat  + (size_t)row * DIM);
    const float4* m4 = (const float4*)(means + (size_t)c   * DIM);
    float4 a0 = f4[lane], a1 = f4[lane + 64];
    float4 b0 = m4[lane], b1 = m4[lane + 64];

    float dot = a0.x * b0.x + a0.y * b0.y + a0.z * b0.z + a0.w * b0.w
              + a1.x * b1.x + a1.y * b1.y + a1.z * b1.z + a1.w * b1.w;
    float nf  = a0.x * a0.x + a0.y * a0.y + a0.z * a0.z + a0.w * a0.w
              + a1.x * a1.x + a1.y * a1.y + a1.z * a1.z + a1.w * a1.w;

    #pragma unroll
    for (int off = 32; off; off >>= 1) {
        dot += __shfl_down(dot, off, 64);
        nf  += __shfl_down(nf,  off, 64);
    }
    if (lane == 0) {
        float nfv = fmaxf(sqrtf(nf), EPSV);
        out[row] = dot * qinv[c] / nfv;
    }
}

extern "C" void kernel_launch(void* const* d_in, const int* in_sizes, int n_in,
                              void* d_out, int out_size, void* d_ws, size_t ws_size,
                              hipStream_t stream) {
    const float* feat  = (const float*)d_in[0];
    const int*   label = (const int*)d_in[1];
    float*       out   = (float*)d_out;
    const int n = in_sizes[0] / DIM;   // 100000

    // workspace layout (floats): sums[100*512] | cnt[128] | means[100*512] | qinv[128]
    float* sums  = (float*)d_ws;
    int*   cnt   = (int*)(sums + NCLS * DIM);
    float* means = (float*)(cnt + 128);
    float* qinv  = means + NCLS * DIM;

    // zero sums + counts
    hipMemsetAsync(d_ws, 0, (NCLS * DIM + 128) * sizeof(float), stream);

    hist_kernel<<<256, 256, 0, stream>>>(label, cnt, n);

    dim3 sg(8, 128);                   // 8 d-chunks x 128 row-chunks = 1024 blocks
    segsum_kernel<<<sg, 256, 0, stream>>>(feat, label, sums, n);

    finalize_kernel<<<NCLS, 256, 0, stream>>>(sums, cnt, means, qinv);

    cos_kernel<<<(n + 3) / 4, 256, 0, stream>>>(feat, label, means, qinv, out, n);
}

// Round 3
// 502.510 us; speedup vs baseline: 1.0028x; 1.0028x over previous
//
#include <hip/hip_runtime.h>
#include <hip/hip_bf16.h>

#define NCLS 100
#define DIM  512
#define EPSV 1e-8f
#define ACCS 65          // padded class stride (floats) to decorrelate atomic banks
#define GY   160         // segsum row-chunks: 8*160 = 1280 blocks = 5/CU
#define MAXROWS 640      // ceil(100000/160)=625 <= 640

// ---------------- histogram of labels ----------------
__global__ __launch_bounds__(256) void hist_kernel(const int* __restrict__ label,
                                                   int* __restrict__ cnt, int n) {
    __shared__ int h[NCLS];
    for (int i = threadIdx.x; i < NCLS; i += 256) h[i] = 0;
    __syncthreads();
    for (int i = blockIdx.x * 256 + threadIdx.x; i < n; i += gridDim.x * 256)
        atomicAdd(&h[label[i]], 1);
    __syncthreads();
    for (int i = threadIdx.x; i < NCLS; i += 256) {
        int v = h[i];
        if (v) atomicAdd(&cnt[i], v);
    }
}

// ---------------- segment sum ----------------
// grid.x = 8 d-chunks of 64 dims, grid.y = GY row chunks. Block = 256 = 4 waves.
// Within a wave: 4 clusters of 16 lanes; cluster handles one row, lane t covers
// dims [4t,4t+3] of the 64-dim chunk via one float4 load. Labels staged in LDS.
__global__ __launch_bounds__(256) void segsum_kernel(const float* __restrict__ feat,
                                                     const int* __restrict__ label,
                                                     float* __restrict__ sums, int n) {
    __shared__ float acc[NCLS * ACCS];   // 26.0 KB
    __shared__ int   slab[MAXROWS];      // 2.5 KB

    const int tid = threadIdx.x;
    for (int i = tid; i < NCLS * ACCS; i += 256) acc[i] = 0.0f;

    const int rows_per = (n + gridDim.y - 1) / gridDim.y;
    const int r0 = blockIdx.y * rows_per;
    const int r1 = min(n, r0 + rows_per);
    const int nrows = r1 - r0;

    for (int i = tid; i < nrows; i += 256) slab[i] = label[r0 + i];
    __syncthreads();

    const int lane  = tid & 63;
    const int wv    = tid >> 6;          // 0..3
    const int cl    = lane >> 4;         // cluster 0..3
    const int t     = lane & 15;         // dim-quarter within 64-dim chunk
    const int dbase = blockIdx.x * 64;

    const float* fbase = feat + (size_t)r0 * DIM + dbase + t * 4;

    // main loop: block consumes 64 rows/iter (wave: 16 rows, 4 per unroll step)
    const int full = (nrows / 64) * 64;
    for (int base = 0; base < full; base += 64) {
        const int rb = base + wv * 16 + cl;
        const int c0 = slab[rb];
        const int c1 = slab[rb + 4];
        const int c2 = slab[rb + 8];
        const int c3 = slab[rb + 12];
        float4 v0 = *(const float4*)(fbase + (size_t)(rb     ) * DIM);
        float4 v1 = *(const float4*)(fbase + (size_t)(rb +  4) * DIM);
        float4 v2 = *(const float4*)(fbase + (size_t)(rb +  8) * DIM);
        float4 v3 = *(const float4*)(fbase + (size_t)(rb + 12) * DIM);
        float* a0 = &acc[c0 * ACCS + t * 4];
        float* a1 = &acc[c1 * ACCS + t * 4];
        float* a2 = &acc[c2 * ACCS + t * 4];
        float* a3 = &acc[c3 * ACCS + t * 4];
        atomicAdd(a0 + 0, v0.x); atomicAdd(a0 + 1, v0.y);
        atomicAdd(a0 + 2, v0.z); atomicAdd(a0 + 3, v0.w);
        atomicAdd(a1 + 0, v1.x); atomicAdd(a1 + 1, v1.y);
        atomicAdd(a1 + 2, v1.z); atomicAdd(a1 + 3, v1.w);
        atomicAdd(a2 + 0, v2.x); atomicAdd(a2 + 1, v2.y);
        atomicAdd(a2 + 2, v2.z); atomicAdd(a2 + 3, v2.w);
        atomicAdd(a3 + 0, v3.x); atomicAdd(a3 + 1, v3.y);
        atomicAdd(a3 + 2, v3.z); atomicAdd(a3 + 3, v3.w);
    }
    // tail
    for (int rb = full + wv * 4 + cl; rb < nrows; rb += 16) {
        const int c = slab[rb];
        float4 v = *(const float4*)(fbase + (size_t)rb * DIM);
        float* a = &acc[c * ACCS + t * 4];
        atomicAdd(a + 0, v.x); atomicAdd(a + 1, v.y);
        atomicAdd(a + 2, v.z); atomicAdd(a + 3, v.w);
    }
    __syncthreads();

    // flush LDS partials to global sums
    for (int i = tid; i < NCLS * 64; i += 256) {
        const int c = i >> 6, d = i & 63;
        float v = acc[c * ACCS + d];
        if (v != 0.0f)
            atomicAdd(&sums[(size_t)c * DIM + dbase + d], v);
    }
}

// ---------------- means + per-class inverse norm ----------------
__global__ __launch_bounds__(256) void finalize_kernel(const float* __restrict__ sums,
                                                       const int* __restrict__ cnt,
                                                       float* __restrict__ means,
                                                       float* __restrict__ qinv) {
    const int c = blockIdx.x;
    const float inv = 1.0f / fmaxf((float)cnt[c], 1.0f);
    __shared__ float red[4];
    float ss = 0.0f;
    for (int d = threadIdx.x; d < DIM; d += 256) {
        float m = sums[(size_t)c * DIM + d] * inv;
        means[(size_t)c * DIM + d] = m;
        ss += m * m;
    }
    #pragma unroll
    for (int off = 32; off; off >>= 1) ss += __shfl_down(ss, off, 64);
    const int wv = threadIdx.x >> 6, ln = threadIdx.x & 63;
    if (ln == 0) red[wv] = ss;
    __syncthreads();
    if (threadIdx.x == 0) {
        float t = red[0] + red[1] + red[2] + red[3];
        qinv[c] = 1.0f / fmaxf(sqrtf(t), EPSV);
    }
}

// ---------------- cosine: 16 lanes per row, 4 rows per wave ----------------
// FIX vs R2: each lane now covers 8 float4s (all 512 dims), not 2.
__global__ __launch_bounds__(256) void cos_kernel(const float* __restrict__ feat,
                                                  const int* __restrict__ label,
                                                  const float* __restrict__ means,
                                                  const float* __restrict__ qinv,
                                                  float* __restrict__ out, int n) {
    const int lane = threadIdx.x & 63;
    const int wv   = threadIdx.x >> 6;
    const int cl   = lane >> 4;
    const int t    = lane & 15;

    const int row = blockIdx.x * 16 + wv * 4 + cl;
    const bool ok = row < n;
    const int rr = ok ? row : (n - 1);

    const int c = label[rr];
    const float4* f4 = (const float4*)(feat  + (size_t)rr * DIM);
    const float4* m4 = (const float4*)(means + (size_t)c  * DIM);

    float4 a[8], b[8];
    #pragma unroll
    for (int j = 0; j < 8; ++j) a[j] = f4[t + 16 * j];
    #pragma unroll
    for (int j = 0; j < 8; ++j) b[j] = m4[t + 16 * j];

    float dot = 0.0f, nf = 0.0f;
    #pragma unroll
    for (int j = 0; j < 8; ++j) {
        dot += a[j].x * b[j].x + a[j].y * b[j].y + a[j].z * b[j].z + a[j].w * b[j].w;
        nf  += a[j].x * a[j].x + a[j].y * a[j].y + a[j].z * a[j].z + a[j].w * a[j].w;
    }

    #pragma unroll
    for (int off = 8; off; off >>= 1) {
        dot += __shfl_xor(dot, off, 64);
        nf  += __shfl_xor(nf,  off, 64);
    }
    if (t == 0 && ok) {
        float nfv = fmaxf(sqrtf(nf), EPSV);
        out[row] = dot * qinv[c] / nfv;
    }
}

extern "C" void kernel_launch(void* const* d_in, const int* in_sizes, int n_in,
                              void* d_out, int out_size, void* d_ws, size_t ws_size,
                              hipStream_t stream) {
    const float* feat  = (const float*)d_in[0];
    const int*   label = (const int*)d_in[1];
    float*       out   = (float*)d_out;
    const int n = in_sizes[0] / DIM;   // 100000

    // workspace layout (floats): sums[100*512] | cnt[128] | means[100*512] | qinv[128]
    float* sums  = (float*)d_ws;
    int*   cnt   = (int*)(sums + NCLS * DIM);
    float* means = (float*)(cnt + 128);
    float* qinv  = means + NCLS * DIM;

    hipMemsetAsync(d_ws, 0, (NCLS * DIM + 128) * sizeof(float), stream);

    hist_kernel<<<256, 256, 0, stream>>>(label, cnt, n);

    dim3 sg(8, GY);                    // 8 d-chunks x 160 row-chunks = 1280 blocks = 5/CU
    segsum_kernel<<<sg, 256, 0, stream>>>(feat, label, sums, n);

    finalize_kernel<<<NCLS, 256, 0, stream>>>(sums, cnt, means, qinv);

    cos_kernel<<<(n + 15) / 16, 256, 0, stream>>>(feat, label, means, qinv, out, n);
}

// Round 4
// 334.346 us; speedup vs baseline: 1.5072x; 1.5030x over previous
//
#include <hip/hip_runtime.h>
#include <hip/hip_bf16.h>

#define NCLS 100
#define DIM  512
#define EPSV 1e-8f
#define NSPLIT 16        // blocks per class in segsum
#define IDXBUF 512       // LDS index staging per batch
#define SCAT_ROWS 1024   // rows per scatter block

// ---------------- histogram of labels ----------------
__global__ __launch_bounds__(256) void hist_kernel(const int* __restrict__ label,
                                                   int* __restrict__ cnt, int n) {
    __shared__ int h[NCLS];
    for (int i = threadIdx.x; i < NCLS; i += 256) h[i] = 0;
    __syncthreads();
    for (int i = blockIdx.x * 256 + threadIdx.x; i < n; i += gridDim.x * 256)
        atomicAdd(&h[label[i]], 1);
    __syncthreads();
    for (int i = threadIdx.x; i < NCLS; i += 256) {
        int v = h[i];
        if (v) atomicAdd(&cnt[i], v);
    }
}

// ---------------- exclusive scan over 100 classes (tiny, serial) ----------------
__global__ void scan_kernel(const int* __restrict__ cnt, int* __restrict__ base,
                            int* __restrict__ cursor) {
    if (threadIdx.x == 0) {
        int s = 0;
        for (int c = 0; c < NCLS; ++c) { base[c] = s; cursor[c] = s; s += cnt[c]; }
    }
}

// ---------------- counting-sort scatter: perm groups rows by class ----------------
__global__ __launch_bounds__(256) void scatter_kernel(const int* __restrict__ label,
                                                      int* __restrict__ cursor,
                                                      int* __restrict__ perm, int n) {
    __shared__ int h[NCLS];
    __shared__ int starts[NCLS];
    const int tid = threadIdx.x;
    for (int i = tid; i < NCLS; i += 256) h[i] = 0;
    __syncthreads();

    const int r0 = blockIdx.x * SCAT_ROWS;
    int c[4], lr[4];
    #pragma unroll
    for (int k = 0; k < 4; ++k) {
        const int r = r0 + k * 256 + tid;
        if (r < n) { c[k] = label[r]; lr[k] = atomicAdd(&h[c[k]], 1); }
        else c[k] = -1;
    }
    __syncthreads();
    for (int i = tid; i < NCLS; i += 256)
        starts[i] = h[i] ? atomicAdd(&cursor[i], h[i]) : 0;
    __syncthreads();
    #pragma unroll
    for (int k = 0; k < 4; ++k)
        if (c[k] >= 0) perm[starts[c[k]] + lr[k]] = r0 + k * 256 + tid;
}

// ---------------- segment sum over sorted rows: zero LDS atomics ----------------
// grid = (NSPLIT, NCLS). Block handles split s of class c: register-accumulates
// its 2 dims over the split's rows; each row is one 2 KB fully-coalesced load.
__global__ __launch_bounds__(256) void segsum_kernel(const float* __restrict__ feat,
                                                     const int* __restrict__ perm,
                                                     const int* __restrict__ base,
                                                     const int* __restrict__ cnt,
                                                     float* __restrict__ sums) {
    const int s = blockIdx.x;
    const int c = blockIdx.y;
    const int m = cnt[c];
    const int b = base[c];
    const int jlo = b + (m * s) / NSPLIT;
    const int jhi = b + (m * (s + 1)) / NSPLIT;

    __shared__ int idx[IDXBUF];
    const int tid = threadIdx.x;
    float2 acc = {0.0f, 0.0f};
    const float* fbase = feat + tid * 2;

    for (int j0 = jlo; j0 < jhi; j0 += IDXBUF) {
        const int batch = min(IDXBUF, jhi - j0);
        __syncthreads();
        for (int i = tid; i < batch; i += 256) idx[i] = perm[j0 + i];
        __syncthreads();
        int i = 0;
        for (; i + 8 <= batch; i += 8) {
            float2 v[8];
            #pragma unroll
            for (int u = 0; u < 8; ++u)
                v[u] = *(const float2*)(fbase + (size_t)idx[i + u] * DIM);
            #pragma unroll
            for (int u = 0; u < 8; ++u) { acc.x += v[u].x; acc.y += v[u].y; }
        }
        for (; i < batch; ++i) {
            float2 v = *(const float2*)(fbase + (size_t)idx[i] * DIM);
            acc.x += v.x; acc.y += v.y;
        }
    }
    if (jhi > jlo) {
        atomicAdd(&sums[(size_t)c * DIM + tid * 2],     acc.x);
        atomicAdd(&sums[(size_t)c * DIM + tid * 2 + 1], acc.y);
    }
}

// ---------------- means + per-class inverse norm ----------------
__global__ __launch_bounds__(256) void finalize_kernel(const float* __restrict__ sums,
                                                       const int* __restrict__ cnt,
                                                       float* __restrict__ means,
                                                       float* __restrict__ qinv) {
    const int c = blockIdx.x;
    const float inv = 1.0f / fmaxf((float)cnt[c], 1.0f);
    __shared__ float red[4];
    float ss = 0.0f;
    for (int d = threadIdx.x; d < DIM; d += 256) {
        float m = sums[(size_t)c * DIM + d] * inv;
        means[(size_t)c * DIM + d] = m;
        ss += m * m;
    }
    #pragma unroll
    for (int off = 32; off; off >>= 1) ss += __shfl_down(ss, off, 64);
    const int wv = threadIdx.x >> 6, ln = threadIdx.x & 63;
    if (ln == 0) red[wv] = ss;
    __syncthreads();
    if (threadIdx.x == 0) {
        float t = red[0] + red[1] + red[2] + red[3];
        qinv[c] = 1.0f / fmaxf(sqrtf(t), EPSV);
    }
}

// ---------------- cosine: 16 lanes per row, 4 rows per wave ----------------
__global__ __launch_bounds__(256) void cos_kernel(const float* __restrict__ feat,
                                                  const int* __restrict__ label,
                                                  const float* __restrict__ means,
                                                  const float* __restrict__ qinv,
                                                  float* __restrict__ out, int n) {
    const int lane = threadIdx.x & 63;
    const int wv   = threadIdx.x >> 6;
    const int cl   = lane >> 4;
    const int t    = lane & 15;

    const int row = blockIdx.x * 16 + wv * 4 + cl;
    const bool ok = row < n;
    const int rr = ok ? row : (n - 1);

    const int c = label[rr];
    const float4* f4 = (const float4*)(feat  + (size_t)rr * DIM);
    const float4* m4 = (const float4*)(means + (size_t)c  * DIM);

    float4 a[8], b[8];
    #pragma unroll
    for (int j = 0; j < 8; ++j) a[j] = f4[t + 16 * j];
    #pragma unroll
    for (int j = 0; j < 8; ++j) b[j] = m4[t + 16 * j];

    float dot = 0.0f, nf = 0.0f;
    #pragma unroll
    for (int j = 0; j < 8; ++j) {
        dot += a[j].x * b[j].x + a[j].y * b[j].y + a[j].z * b[j].z + a[j].w * b[j].w;
        nf  += a[j].x * a[j].x + a[j].y * a[j].y + a[j].z * a[j].z + a[j].w * a[j].w;
    }

    #pragma unroll
    for (int off = 8; off; off >>= 1) {
        dot += __shfl_xor(dot, off, 64);
        nf  += __shfl_xor(nf,  off, 64);
    }
    if (t == 0 && ok) {
        float nfv = fmaxf(sqrtf(nf), EPSV);
        out[row] = dot * qinv[c] / nfv;
    }
}

extern "C" void kernel_launch(void* const* d_in, const int* in_sizes, int n_in,
                              void* d_out, int out_size, void* d_ws, size_t ws_size,
                              hipStream_t stream) {
    const float* feat  = (const float*)d_in[0];
    const int*   label = (const int*)d_in[1];
    float*       out   = (float*)d_out;
    const int n = in_sizes[0] / DIM;   // 100000

    // ws layout (4 B units):
    // sums[100*512] | cnt[128] | means[100*512] | qinv[128] | base[128] | cursor[128] | perm[n]
    float* sums   = (float*)d_ws;
    int*   cnt    = (int*)(sums + NCLS * DIM);
    float* means  = (float*)(cnt + 128);
    float* qinv   = means + NCLS * DIM;
    int*   base   = (int*)(qinv + 128);
    int*   cursor = base + 128;
    int*   perm   = cursor + 128;

    // zero sums + cnt (ws is poisoned 0xAA before every call)
    hipMemsetAsync(d_ws, 0, (NCLS * DIM + 128) * sizeof(float), stream);

    hist_kernel<<<160, 256, 0, stream>>>(label, cnt, n);
    scan_kernel<<<1, 64, 0, stream>>>(cnt, base, cursor);
    scatter_kernel<<<(n + SCAT_ROWS - 1) / SCAT_ROWS, 256, 0, stream>>>(label, cursor, perm, n);

    dim3 sg(NSPLIT, NCLS);             // 1600 blocks
    segsum_kernel<<<sg, 256, 0, stream>>>(feat, perm, base, cnt, sums);

    finalize_kernel<<<NCLS, 256, 0, stream>>>(sums, cnt, means, qinv);

    cos_kernel<<<(n + 15) / 16, 256, 0, stream>>>(feat, label, means, qinv, out, n);
}

// Round 5
// 332.011 us; speedup vs baseline: 1.5177x; 1.0070x over previous
//
#include <hip/hip_runtime.h>
#include <hip/hip_bf16.h>

#define NCLS 100
#define DIM  512
#define EPSV 1e-8f
#define NSPLIT 16        // blocks per class in segsum
#define IDXBUF 512       // LDS index staging per batch
#define SCAT_ROWS 1024   // rows per scatter block

// ---------------- histogram of labels ----------------
__global__ __launch_bounds__(256) void hist_kernel(const int* __restrict__ label,
                                                   int* __restrict__ cnt, int n) {
    __shared__ int h[NCLS];
    for (int i = threadIdx.x; i < NCLS; i += 256) h[i] = 0;
    __syncthreads();
    for (int i = blockIdx.x * 256 + threadIdx.x; i < n; i += gridDim.x * 256)
        atomicAdd(&h[label[i]], 1);
    __syncthreads();
    for (int i = threadIdx.x; i < NCLS; i += 256) {
        int v = h[i];
        if (v) atomicAdd(&cnt[i], v);
    }
}

// ---------------- parallel exclusive scan over 100 classes ----------------
__global__ __launch_bounds__(128) void scan_kernel(const int* __restrict__ cnt,
                                                   int* __restrict__ base,
                                                   int* __restrict__ cursor) {
    __shared__ int a[128];
    const int t = threadIdx.x;
    a[t] = (t < NCLS) ? cnt[t] : 0;
    __syncthreads();
    // Hillis-Steele inclusive scan on 128
    #pragma unroll
    for (int off = 1; off < 128; off <<= 1) {
        int v = (t >= off) ? a[t - off] : 0;
        __syncthreads();
        a[t] += v;
        __syncthreads();
    }
    if (t < NCLS) {
        int excl = a[t] - cnt[t];   // inclusive -> exclusive
        base[t] = excl;
        cursor[t] = excl;
    }
}

// ---------------- counting-sort scatter: perm groups rows by class ----------------
__global__ __launch_bounds__(256) void scatter_kernel(const int* __restrict__ label,
                                                      int* __restrict__ cursor,
                                                      int* __restrict__ perm, int n) {
    __shared__ int h[NCLS];
    __shared__ int starts[NCLS];
    const int tid = threadIdx.x;
    for (int i = tid; i < NCLS; i += 256) h[i] = 0;
    __syncthreads();

    const int r0 = blockIdx.x * SCAT_ROWS;
    int c[4], lr[4];
    #pragma unroll
    for (int k = 0; k < 4; ++k) {
        const int r = r0 + k * 256 + tid;
        if (r < n) { c[k] = label[r]; lr[k] = atomicAdd(&h[c[k]], 1); }
        else c[k] = -1;
    }
    __syncthreads();
    for (int i = tid; i < NCLS; i += 256)
        starts[i] = h[i] ? atomicAdd(&cursor[i], h[i]) : 0;
    __syncthreads();
    #pragma unroll
    for (int k = 0; k < 4; ++k)
        if (c[k] >= 0) perm[starts[c[k]] + lr[k]] = r0 + k * 256 + tid;
}

// ---------------- segment sum over sorted rows ----------------
// grid = (NSPLIT, NCLS). Thread covers 4 dims (float4); 128 threads span a row,
// the block processes 2 rows in parallel, unrolled 8x (16 rows/iter).
__global__ __launch_bounds__(256) void segsum_kernel(const float* __restrict__ feat,
                                                     const int* __restrict__ perm,
                                                     const int* __restrict__ base,
                                                     const int* __restrict__ cnt,
                                                     float* __restrict__ sums) {
    const int s = blockIdx.x;
    const int c = blockIdx.y;
    const int m = cnt[c];
    const int b = base[c];
    const int jlo = b + (m * s) / NSPLIT;
    const int jhi = b + (m * (s + 1)) / NSPLIT;

    __shared__ int idx[IDXBUF];
    const int tid  = threadIdx.x;
    const int half = tid >> 7;          // row parity
    const int dq   = (tid & 127) * 4;   // dim offset

    float4 acc = {0.0f, 0.0f, 0.0f, 0.0f};

    for (int j0 = jlo; j0 < jhi; j0 += IDXBUF) {
        const int batch = min(IDXBUF, jhi - j0);
        __syncthreads();
        for (int i = tid; i < batch; i += 256) idx[i] = perm[j0 + i];
        __syncthreads();
        int i = half;
        for (; i + 14 < batch; i += 16) {
            float4 v[8];
            #pragma unroll
            for (int u = 0; u < 8; ++u)
                v[u] = *(const float4*)(feat + (size_t)idx[i + 2 * u] * DIM + dq);
            #pragma unroll
            for (int u = 0; u < 8; ++u) {
                acc.x += v[u].x; acc.y += v[u].y; acc.z += v[u].z; acc.w += v[u].w;
            }
        }
        for (; i < batch; i += 2) {
            float4 v = *(const float4*)(feat + (size_t)idx[i] * DIM + dq);
            acc.x += v.x; acc.y += v.y; acc.z += v.z; acc.w += v.w;
        }
    }
    if (m > 0) {
        float* dst = &sums[(size_t)c * DIM + dq];
        atomicAdd(dst + 0, acc.x); atomicAdd(dst + 1, acc.y);
        atomicAdd(dst + 2, acc.z); atomicAdd(dst + 3, acc.w);
    }
}

// ---------------- normalized means: mhat = mean / max(||mean||, eps) ----------------
__global__ __launch_bounds__(256) void finalize_kernel(const float* __restrict__ sums,
                                                       const int* __restrict__ cnt,
                                                       float* __restrict__ mhat) {
    const int c = blockIdx.x;
    const float inv = 1.0f / fmaxf((float)cnt[c], 1.0f);
    const int t = threadIdx.x;
    float m0 = sums[(size_t)c * DIM + t] * inv;
    float m1 = sums[(size_t)c * DIM + 256 + t] * inv;
    float ss = m0 * m0 + m1 * m1;
    #pragma unroll
    for (int off = 32; off; off >>= 1) ss += __shfl_down(ss, off, 64);
    __shared__ float red[4];
    if ((t & 63) == 0) red[t >> 6] = ss;
    __syncthreads();
    const float tot = red[0] + red[1] + red[2] + red[3];
    const float q = 1.0f / fmaxf(sqrtf(tot), EPSV);
    mhat[(size_t)c * DIM + t] = m0 * q;
    mhat[(size_t)c * DIM + 256 + t] = m1 * q;
}

// ---------------- cosine: 16 lanes per row, 4 rows per wave ----------------
__global__ __launch_bounds__(256) void cos_kernel(const float* __restrict__ feat,
                                                  const int* __restrict__ label,
                                                  const float* __restrict__ mhat,
                                                  float* __restrict__ out, int n) {
    const int lane = threadIdx.x & 63;
    const int wv   = threadIdx.x >> 6;
    const int cl   = lane >> 4;
    const int t    = lane & 15;

    const int row = blockIdx.x * 16 + wv * 4 + cl;
    const bool ok = row < n;
    const int rr = ok ? row : (n - 1);

    const int c = label[rr];
    const float4* f4 = (const float4*)(feat + (size_t)rr * DIM);
    const float4* m4 = (const float4*)(mhat + (size_t)c  * DIM);

    float4 a[8], b[8];
    #pragma unroll
    for (int j = 0; j < 8; ++j) a[j] = f4[t + 16 * j];
    #pragma unroll
    for (int j = 0; j < 8; ++j) b[j] = m4[t + 16 * j];

    float dot = 0.0f, nf = 0.0f;
    #pragma unroll
    for (int j = 0; j < 8; ++j) {
        dot += a[j].x * b[j].x + a[j].y * b[j].y + a[j].z * b[j].z + a[j].w * b[j].w;
        nf  += a[j].x * a[j].x + a[j].y * a[j].y + a[j].z * a[j].z + a[j].w * a[j].w;
    }

    #pragma unroll
    for (int off = 8; off; off >>= 1) {
        dot += __shfl_xor(dot, off, 64);
        nf  += __shfl_xor(nf,  off, 64);
    }
    if (t == 0 && ok) {
        out[row] = dot / fmaxf(sqrtf(nf), EPSV);
    }
}

extern "C" void kernel_launch(void* const* d_in, const int* in_sizes, int n_in,
                              void* d_out, int out_size, void* d_ws, size_t ws_size,
                              hipStream_t stream) {
    const float* feat  = (const float*)d_in[0];
    const int*   label = (const int*)d_in[1];
    float*       out   = (float*)d_out;
    const int n = in_sizes[0] / DIM;   // 100000

    // ws layout (4 B units):
    // sums[100*512] | cnt[128] | mhat[100*512] | base[128] | cursor[128] | perm[n]
    float* sums   = (float*)d_ws;
    int*   cnt    = (int*)(sums + NCLS * DIM);
    float* mhat   = (float*)(cnt + 128);
    int*   base   = (int*)(mhat + NCLS * DIM);
    int*   cursor = base + 128;
    int*   perm   = cursor + 128;

    // zero sums + cnt (ws is poisoned 0xAA before every call)
    hipMemsetAsync(d_ws, 0, (NCLS * DIM + 128) * sizeof(float), stream);

    hist_kernel<<<160, 256, 0, stream>>>(label, cnt, n);
    scan_kernel<<<1, 128, 0, stream>>>(cnt, base, cursor);
    scatter_kernel<<<(n + SCAT_ROWS - 1) / SCAT_ROWS, 256, 0, stream>>>(label, cursor, perm, n);

    dim3 sg(NSPLIT, NCLS);             // 1600 blocks
    segsum_kernel<<<sg, 256, 0, stream>>>(feat, perm, base, cnt, sums);

    finalize_kernel<<<NCLS, 256, 0, stream>>>(sums, cnt, mhat);

    cos_kernel<<<(n + 15) / 16, 256, 0, stream>>>(feat, label, mhat, out, n);
}